// Round 20
// baseline (152.286 us; speedup 1.0000x reference)
//
#include <hip/hip_runtime.h>
#include <hip/hip_bf16.h>
#include <math.h>

#define NTOT 110592   // 48^3
#define SD 48
#define SWD 2304      // 48*48

typedef short s16x8 __attribute__((ext_vector_type(8)));
typedef unsigned short u16x8 __attribute__((ext_vector_type(8)));
typedef unsigned short u16x4 __attribute__((ext_vector_type(4)));
typedef float f32x4 __attribute__((ext_vector_type(4)));
typedef unsigned short u16;

__device__ __forceinline__ float bf2f(u16 u) {
    unsigned int x = ((unsigned int)u) << 16;
    float f; __builtin_memcpy(&f, &x, 4); return f;
}
__device__ __forceinline__ u16 f2bf(float f) {
    __hip_bfloat16 h = __float2bfloat16(f);
    u16 u; __builtin_memcpy(&u, &h, 2); return u;
}
__device__ __forceinline__ u16x8 zero8() {
    u16x8 z;
    #pragma unroll
    for (int j = 0; j < 8; ++j) z[j] = 0;
    return z;
}

// fast GELU (tanh form)
__device__ __forceinline__ float gelu_f(float x) {
    float y = x * (0.7978845608f + 0.0356774081f * x * x);
    float e = exp2f(y * 2.885390082f);
    return x - x * __builtin_amdgcn_rcpf(e + 1.f);
}

// XCD-chunked bijective remaps
__device__ __forceinline__ int xcd_swz1728(int bid) { return (bid & 7) * 216 + (bid >> 3); }
__device__ __forceinline__ int xcd_swz864(int bid)  { return (bid & 7) * 108 + (bid >> 3); }

// load shifted h[n][cbase..cbase+7] (bf16), axial shift along stride STR.
__device__ __forceinline__ u16x8 ld_shift8(const u16* __restrict__ in, int n, int coord,
                                           int STR, int cbase) {
    int g = cbase / 26;
    int split = 26 * (g + 1) - cbase;
    int sh0 = g - 2;
    int cs0 = coord - sh0;
    u16x8 lo = zero8();
    if (cs0 >= 0 && cs0 < SD) lo = *(const u16x8*)&in[(size_t)(n - sh0 * STR) * 128 + cbase];
    if (split >= 8) return lo;
    u16x8 hi = zero8();
    int cs1 = cs0 - 1;
    if (cs1 >= 0 && cs1 < SD) hi = *(const u16x8*)&in[(size_t)(n - (sh0 + 1) * STR) * 128 + cbase];
    u16x8 r;
    #pragma unroll
    for (int j = 0; j < 8; ++j) r[j] = (j < split) ? lo[j] : hi[j];
    return r;
}

// shifted gather from t with FUSED LN2 (axis H), zero-fill at boundaries.
__device__ __forceinline__ s16x8 ld_shift8_ln(const u16* __restrict__ t,
                                              const float* __restrict__ mrs,
                                              const float* __restrict__ g2,
                                              const float* __restrict__ b2,
                                              int n, int coord, int STR, int cbase) {
    int g = cbase / 26;
    int split = 26 * (g + 1) - cbase;
    int sh0 = g - 2;
    int cs0 = coord - sh0;
    float gg[8], bb[8];
    {
        f32x4 ga = *(const f32x4*)&g2[cbase];
        f32x4 gb = *(const f32x4*)&g2[cbase + 4];
        f32x4 ba = *(const f32x4*)&b2[cbase];
        f32x4 bbv = *(const f32x4*)&b2[cbase + 4];
        #pragma unroll
        for (int j = 0; j < 4; ++j) {
            gg[j] = ga[j]; gg[j + 4] = gb[j];
            bb[j] = ba[j]; bb[j + 4] = bbv[j];
        }
    }
    float lo[8];
    bool lov = (cs0 >= 0 && cs0 < SD);
    if (lov) {
        int r = n - sh0 * STR;
        u16x8 raw = *(const u16x8*)&t[(size_t)r * 128 + cbase];
        float m = mrs[2 * r], rs = mrs[2 * r + 1];
        #pragma unroll
        for (int j = 0; j < 8; ++j)
            lo[j] = (bf2f(raw[j]) - m) * rs * gg[j] + bb[j];
    } else {
        #pragma unroll
        for (int j = 0; j < 8; ++j) lo[j] = 0.f;
    }
    s16x8 out;
    if (split >= 8) {
        #pragma unroll
        for (int j = 0; j < 8; ++j) out[j] = (short)f2bf(lo[j]);
        return out;
    }
    float hi[8];
    int cs1 = cs0 - 1;
    bool hiv = (cs1 >= 0 && cs1 < SD);
    if (hiv) {
        int r = n - (sh0 + 1) * STR;
        u16x8 raw = *(const u16x8*)&t[(size_t)r * 128 + cbase];
        float m = mrs[2 * r], rs = mrs[2 * r + 1];
        #pragma unroll
        for (int j = 0; j < 8; ++j)
            hi[j] = (bf2f(raw[j]) - m) * rs * gg[j] + bb[j];
    } else {
        #pragma unroll
        for (int j = 0; j < 8; ++j) hi[j] = 0.f;
    }
    #pragma unroll
    for (int j = 0; j < 8; ++j)
        out[j] = (short)f2bf((j < split) ? lo[j] : hi[j]);
    return out;
}

// im2col gather of 4 A-fragments for proj (permuted K)
__device__ __forceinline__ void proj_gather(const float* __restrict__ x, int n, int q,
                                            s16x8 a4[4]) {
    int oi = n / SWD;
    int rem = n - oi * SWD;
    int oj = rem / SD;
    int ok = rem - oj * SD;
    int ii0 = 2 * oi - 1, ij0 = 2 * oj - 1, ik0 = 2 * ok - 1;
    #pragma unroll
    for (int s = 0; s < 4; ++s) {
        #pragma unroll
        for (int d = 0; d < 2; ++d) {
            int tq = 2 * q + d;
            int tau = s * 8 + tq;
            u16 v4[4] = {0, 0, 0, 0};
            bool valid = (s < 3) || (tq < 3);   // tau < 27
            if (valid) {
                int ti = (tau >= 18 ? 1 : 0) + (tau >= 9 ? 1 : 0);
                int r2 = tau - ti * 9;
                int tj = (r2 >= 6 ? 1 : 0) + (r2 >= 3 ? 1 : 0);
                int tk = r2 - tj * 3;
                int ii = ii0 + ti, ij = ij0 + tj, ik = ik0 + tk;
                if (ii >= 0 && ij >= 0 && ik >= 0) {
                    size_t off = ((size_t)ii * 96 + ij) * 96 + ik;
                    #pragma unroll
                    for (int ci = 0; ci < 4; ++ci)
                        v4[ci] = f2bf(x[(size_t)ci * 884736 + off]);
                }
            }
            a4[s][4 * d + 0] = (short)v4[0]; a4[s][4 * d + 1] = (short)v4[1];
            a4[s][4 * d + 2] = (short)v4[2]; a4[s][4 * d + 3] = (short)v4[3];
        }
    }
}

// ---------------------------------------------------------------------------
// merged prep (unchanged)
__global__ __launch_bounds__(256) void k_prep(
    const float* __restrict__ pw, const float* __restrict__ fc1w,
    const float* __restrict__ fc2w, const float* __restrict__ fc3w,
    const float* __restrict__ dw1w, const float* __restrict__ dw2w,
    u16* __restrict__ wfP, u16* __restrict__ wf1, u16* __restrict__ wf2,
    u16* __restrict__ wf3, float* __restrict__ dwT1, float* __restrict__ dwT2)
{
    int b = blockIdx.x;
    if (b < 32) {
        int which = b >> 3;
        const float* src = (which == 0) ? pw : (which == 1) ? fc1w : (which == 2) ? fc2w : fc3w;
        u16* dst = (which == 0) ? wfP : (which == 1) ? wf1 : (which == 2) ? wf2 : wf3;
        int idx = (b & 7) * 256 + threadIdx.x;
        int lane = idx & 63;
        int s = (idx >> 6) & 3;
        int t = idx >> 8;
        int co = t * 16 + (lane & 15);
        int kb = s * 32 + (lane >> 4) * 8;
        #pragma unroll
        for (int j = 0; j < 8; ++j) {
            int kk = kb + j;
            float v;
            if (which == 0) {
                int tau = kk >> 2, ci = kk & 3;
                v = (tau < 27) ? src[co * 108 + ci * 27 + tau] : 0.f;
            } else {
                v = src[co * 128 + kk];
            }
            dst[idx * 8 + j] = f2bf(v);
        }
    } else {
        int which = (b - 32) / 14;
        int bb = (b - 32) % 14;
        const float* src = which ? dw2w : dw1w;
        float* dst = which ? dwT2 : dwT1;
        int idx = bb * 256 + threadIdx.x;
        if (idx < 27 * 128) {
            int k = idx >> 7;
            int co = idx & 127;
            dst[idx] = src[co * 27 + k];
        }
    }
}

// ---------------------------------------------------------------------------
// proj conv + LN0 -> t + LN2 stats -> mrs. 2-tile block (128 rows):
// wfl staged ONCE, then two sequential 64-row tiles. XCD swizzle (864).
__global__ __launch_bounds__(256) void k_proj_ln(
    const float* __restrict__ x, const u16* __restrict__ wfrag, const float* __restrict__ pb,
    const float* __restrict__ g0, const float* __restrict__ b0,
    u16* __restrict__ t_out, float* __restrict__ mrs)
{
    __shared__ __align__(16) u16 wfl[16384];   // 32 KB weight frags
    const int tid = threadIdx.x;
    const int nb = xcd_swz864(blockIdx.x) * 128;
    const int lane = tid & 63;
    const int wv = tid >> 6;
    const int colb = lane & 15;
    const int q = lane >> 4;
    const int arow = wv * 16 + colb;

    for (int i = tid; i < 2048; i += 256)
        *(u16x8*)&wfl[i * 8] = *(const u16x8*)&wfrag[i * 8];

    float pbr[8], g0v[8], b0v[8];
    #pragma unroll
    for (int t = 0; t < 8; ++t) {
        int c = t * 16 + colb;
        pbr[t] = pb[c]; g0v[t] = g0[c]; b0v[t] = b0[c];
    }

    s16x8 a4[4];
    proj_gather(x, nb + arow, q, a4);   // tile-0 gather overlaps staging
    __syncthreads();   // wfl ready

    #pragma unroll
    for (int sub = 0; sub < 2; ++sub) {
        const int n0 = nb + sub * 64;
        if (sub) proj_gather(x, n0 + arow, q, a4);

        f32x4 acc[8];
        #pragma unroll
        for (int t = 0; t < 8; ++t) {
            acc[t][0] = pbr[t]; acc[t][1] = pbr[t]; acc[t][2] = pbr[t]; acc[t][3] = pbr[t];
        }
        #pragma unroll
        for (int s = 0; s < 4; ++s) {
            s16x8 bf[8];
            #pragma unroll
            for (int t = 0; t < 8; ++t)
                bf[t] = *(const s16x8*)&wfl[((t * 4 + s) * 64 + lane) * 8];
            #pragma unroll
            for (int t = 0; t < 8; ++t)
                acc[t] = __builtin_amdgcn_mfma_f32_16x16x32_bf16(a4[s], bf[t], acc[t], 0, 0, 0);
        }

        float s1[4] = {0.f,0.f,0.f,0.f}, s2[4] = {0.f,0.f,0.f,0.f};
        #pragma unroll
        for (int t = 0; t < 8; ++t)
            #pragma unroll
            for (int r4 = 0; r4 < 4; ++r4) {
                float v = acc[t][r4];
                s1[r4] += v; s2[r4] += v * v;
            }
        #pragma unroll
        for (int r4 = 0; r4 < 4; ++r4)
            #pragma unroll
            for (int m = 1; m < 16; m <<= 1) {
                s1[r4] += __shfl_xor(s1[r4], m);
                s2[r4] += __shfl_xor(s2[r4], m);
            }

        float tval[8][4];
        float u1[4] = {0.f,0.f,0.f,0.f}, u2[4] = {0.f,0.f,0.f,0.f};
        #pragma unroll
        for (int r4 = 0; r4 < 4; ++r4) {
            float mean = s1[r4] * (1.f / 128.f);
            float var  = fmaxf(s2[r4] * (1.f / 128.f) - mean * mean, 0.f);
            float rstd = rsqrtf(var + 1e-5f);
            #pragma unroll
            for (int t = 0; t < 8; ++t) {
                float tv = (acc[t][r4] - mean) * rstd * g0v[t] + b0v[t];
                tval[t][r4] = tv;
                u1[r4] += tv; u2[r4] += tv * tv;
            }
        }
        #pragma unroll
        for (int r4 = 0; r4 < 4; ++r4) {
            #pragma unroll
            for (int m = 1; m < 16; m <<= 1) {
                u1[r4] += __shfl_xor(u1[r4], m);
                u2[r4] += __shfl_xor(u2[r4], m);
            }
        }

        #pragma unroll
        for (int r4 = 0; r4 < 4; ++r4) {
            float mean2 = u1[r4] * (1.f / 128.f);
            float var2  = fmaxf(u2[r4] * (1.f / 128.f) - mean2 * mean2, 0.f);
            float rstd2 = rsqrtf(var2 + 1e-5f);
            int row = wv * 16 + q * 4 + r4;
            size_t base = (size_t)(n0 + row) * 128;
            #pragma unroll
            for (int t = 0; t < 8; ++t)
                t_out[base + t * 16 + colb] = f2bf(tval[t][r4]);
            if (colb == 0) {
                mrs[2 * (n0 + row) + 0] = mean2;
                mrs[2 * (n0 + row) + 1] = rstd2;
            }
        }
    }
}

// ---------------------------------------------------------------------------
// axial shift + FUSED LN2 + matmul (axis H). 2-tile block, XCD swizzle (864).
__global__ __launch_bounds__(256) void k_shift_mm_ln(
    const u16* __restrict__ tin, const float* __restrict__ mrs,
    const float* __restrict__ g2, const float* __restrict__ b2,
    const u16* __restrict__ wfrag, const float* __restrict__ bias,
    u16* __restrict__ out)
{
    __shared__ __align__(16) u16 wfl[16384];
    const int tid = threadIdx.x;
    const int nb = xcd_swz864(blockIdx.x) * 128;
    const int lane = tid & 63;
    const int wv = tid >> 6;
    const int colb = lane & 15;
    const int q = lane >> 4;
    const int arow = wv * 16 + colb;

    for (int i = tid; i < 2048; i += 256)
        *(u16x8*)&wfl[i * 8] = *(const u16x8*)&wfrag[i * 8];

    float biasr[8];
    #pragma unroll
    for (int t = 0; t < 8; ++t) biasr[t] = bias[t * 16 + colb];

    s16x8 a4[4];
    {
        int n = nb + arow;
        int coord = n / SWD;
        #pragma unroll
        for (int s = 0; s < 4; ++s)
            a4[s] = ld_shift8_ln(tin, mrs, g2, b2, n, coord, SWD, s * 32 + q * 8);
    }
    __syncthreads();

    #pragma unroll
    for (int sub = 0; sub < 2; ++sub) {
        const int n0 = nb + sub * 64;
        const int n = n0 + arow;
        if (sub) {
            int coord = n / SWD;
            #pragma unroll
            for (int s = 0; s < 4; ++s)
                a4[s] = ld_shift8_ln(tin, mrs, g2, b2, n, coord, SWD, s * 32 + q * 8);
        }
        f32x4 acc[8];
        #pragma unroll
        for (int t = 0; t < 8; ++t) {
            acc[t][0] = biasr[t]; acc[t][1] = biasr[t]; acc[t][2] = biasr[t]; acc[t][3] = biasr[t];
        }
        #pragma unroll
        for (int s = 0; s < 4; ++s) {
            s16x8 bf[8];
            #pragma unroll
            for (int t = 0; t < 8; ++t)
                bf[t] = *(const s16x8*)&wfl[((t * 4 + s) * 64 + lane) * 8];
            #pragma unroll
            for (int t = 0; t < 8; ++t)
                acc[t] = __builtin_amdgcn_mfma_f32_16x16x32_bf16(a4[s], bf[t], acc[t], 0, 0, 0);
        }
        #pragma unroll
        for (int r4 = 0; r4 < 4; ++r4) {
            int row = wv * 16 + q * 4 + r4;
            size_t base = (size_t)(n0 + row) * 128;
            #pragma unroll
            for (int t = 0; t < 8; ++t)
                out[base + t * 16 + colb] = f2bf(acc[t][r4]);
        }
    }
}

// ---------------------------------------------------------------------------
// axial shift + matmul (plain, axis W). 2-tile block, XCD swizzle (864).
template <int AXIS>
__global__ __launch_bounds__(256) void k_shift_mm(
    const u16* __restrict__ in, const u16* __restrict__ wfrag, const float* __restrict__ bias,
    u16* __restrict__ out)
{
    __shared__ __align__(16) u16 wfl[16384];
    const int tid = threadIdx.x;
    const int nb = xcd_swz864(blockIdx.x) * 128;
    const int lane = tid & 63;
    const int wv = tid >> 6;
    const int colb = lane & 15;
    const int q = lane >> 4;
    const int arow = wv * 16 + colb;
    const int STR = (AXIS == 0) ? SWD : (AXIS == 1) ? SD : 1;

    for (int i = tid; i < 2048; i += 256)
        *(u16x8*)&wfl[i * 8] = *(const u16x8*)&wfrag[i * 8];

    float biasr[8];
    #pragma unroll
    for (int t = 0; t < 8; ++t) biasr[t] = bias[t * 16 + colb];

    s16x8 a4[4];
    {
        int n = nb + arow;
        int coord = (AXIS == 0) ? n / SWD : (AXIS == 1) ? (n / SD) % SD : n % SD;
        #pragma unroll
        for (int s = 0; s < 4; ++s) {
            u16x8 av = ld_shift8(in, n, coord, STR, s * 32 + q * 8);
            a4[s] = *(s16x8*)&av;
        }
    }
    __syncthreads();

    #pragma unroll
    for (int sub = 0; sub < 2; ++sub) {
        const int n0 = nb + sub * 64;
        const int n = n0 + arow;
        if (sub) {
            int coord = (AXIS == 0) ? n / SWD : (AXIS == 1) ? (n / SD) % SD : n % SD;
            #pragma unroll
            for (int s = 0; s < 4; ++s) {
                u16x8 av = ld_shift8(in, n, coord, STR, s * 32 + q * 8);
                a4[s] = *(s16x8*)&av;
            }
        }
        f32x4 acc[8];
        #pragma unroll
        for (int t = 0; t < 8; ++t) {
            acc[t][0] = biasr[t]; acc[t][1] = biasr[t]; acc[t][2] = biasr[t]; acc[t][3] = biasr[t];
        }
        #pragma unroll
        for (int s = 0; s < 4; ++s) {
            s16x8 bf[8];
            #pragma unroll
            for (int t = 0; t < 8; ++t)
                bf[t] = *(const s16x8*)&wfl[((t * 4 + s) * 64 + lane) * 8];
            #pragma unroll
            for (int t = 0; t < 8; ++t)
                acc[t] = __builtin_amdgcn_mfma_f32_16x16x32_bf16(a4[s], bf[t], acc[t], 0, 0, 0);
        }
        #pragma unroll
        for (int r4 = 0; r4 < 4; ++r4) {
            int row = wv * 16 + q * 4 + r4;
            size_t base = (size_t)(n0 + row) * 128;
            #pragma unroll
            for (int t = 0; t < 8; ++t)
                out[base + t * 16 + colb] = f2bf(acc[t][r4]);
        }
    }
}

// ---------------------------------------------------------------------------
// depthwise 3x3x3 conv (unchanged)
__global__ __launch_bounds__(256, 4) void k_dw(
    const u16* __restrict__ in, const float* __restrict__ wt, const float* __restrict__ b,
    u16* __restrict__ out)
{
    __shared__ __align__(16) float wtl[27 * 128];
    const int tid = threadIdx.x;
    const int cg = tid & 15;
    const int kq = tid >> 4;
    const int k0 = kq * 3;
    const int bid = blockIdx.x;
    const int ij = (bid & 7) * 288 + (bid >> 3);
    const int i = ij / SD;
    const int j = ij - i * SD;
    const int c = cg * 8;

    for (int t = tid; t < 864; t += 256)
        ((float4*)wtl)[t] = ((const float4*)wt)[t];

    const int kclamp0 = (k0 - 1 < 0) ? 0 : (k0 - 1);
    const int kclamp4 = (k0 + 3 > SD - 1) ? (SD - 1) : (k0 + 3);
    const bool k0bad = (k0 - 1 < 0);
    const bool k4bad = (k0 + 3 > SD - 1);

    float acc[3][8];
    {
        float4 ba = *(const float4*)&b[c];
        float4 bb = *(const float4*)&b[c + 4];
        #pragma unroll
        for (int t = 0; t < 3; ++t) {
            acc[t][0] = ba.x; acc[t][1] = ba.y; acc[t][2] = ba.z; acc[t][3] = ba.w;
            acc[t][4] = bb.x; acc[t][5] = bb.y; acc[t][6] = bb.z; acc[t][7] = bb.w;
        }
    }

    bool okt[9];
    const u16* baseptr[9];
    #pragma unroll
    for (int t9 = 0; t9 < 9; ++t9) {
        int di = t9 / 3 - 1, dj = t9 % 3 - 1;
        int ii = i + di, jj = j + dj;
        okt[t9] = ((unsigned)ii < SD) && ((unsigned)jj < SD);
        int iic = (ii < 0) ? 0 : (ii > SD - 1 ? SD - 1 : ii);
        int jjc = (jj < 0) ? 0 : (jj > SD - 1 ? SD - 1 : jj);
        baseptr[t9] = &in[(size_t)((iic * SD + jjc) * SD) * 128 + c];
    }

    u16x8 win[2][5];
    {
        const u16* base = baseptr[0];
        win[0][0] = *(const u16x8*)(base + (size_t)kclamp0 * 128);
        win[0][1] = *(const u16x8*)(base + (size_t)(k0    ) * 128);
        win[0][2] = *(const u16x8*)(base + (size_t)(k0 + 1) * 128);
        win[0][3] = *(const u16x8*)(base + (size_t)(k0 + 2) * 128);
        win[0][4] = *(const u16x8*)(base + (size_t)kclamp4 * 128);
    }
    __syncthreads();

    #pragma unroll
    for (int t9 = 0; t9 < 9; ++t9) {
        const int cur = t9 & 1;
        if (t9 < 8) {
            const u16* base = baseptr[t9 + 1];
            win[cur ^ 1][0] = *(const u16x8*)(base + (size_t)kclamp0 * 128);
            win[cur ^ 1][1] = *(const u16x8*)(base + (size_t)(k0    ) * 128);
            win[cur ^ 1][2] = *(const u16x8*)(base + (size_t)(k0 + 1) * 128);
            win[cur ^ 1][3] = *(const u16x8*)(base + (size_t)(k0 + 2) * 128);
            win[cur ^ 1][4] = *(const u16x8*)(base + (size_t)kclamp4 * 128);
        }
        if (okt[t9]) {
            const int tap0 = t9 * 3;
            float wv[3][8];
            #pragma unroll
            for (int dk = 0; dk < 3; ++dk) {
                float4 wa = *(const float4*)&wtl[(tap0 + dk) * 128 + c];
                float4 wb = *(const float4*)&wtl[(tap0 + dk) * 128 + c + 4];
                wv[dk][0] = wa.x; wv[dk][1] = wa.y; wv[dk][2] = wa.z; wv[dk][3] = wa.w;
                wv[dk][4] = wb.x; wv[dk][5] = wb.y; wv[dk][6] = wb.z; wv[dk][7] = wb.w;
            }
            #pragma unroll
            for (int s = 0; s < 5; ++s) {
                bool bad = (s == 0 && k0bad) || (s == 4 && k4bad);
                float vs[8];
                #pragma unroll
                for (int m = 0; m < 8; ++m)
                    vs[m] = bad ? 0.f : bf2f(win[cur][s][m]);
                #pragma unroll
                for (int t = 0; t < 3; ++t) {
                    int dk = s - t;
                    if (dk >= 0 && dk < 3) {
                        #pragma unroll
                        for (int m = 0; m < 8; ++m)
                            acc[t][m] = fmaf(wv[dk][m], vs[m], acc[t][m]);
                    }
                }
            }
        }
    }
    #pragma unroll
    for (int t = 0; t < 3; ++t) {
        u16x8 o;
        #pragma unroll
        for (int m = 0; m < 8; ++m) o[m] = f2bf(acc[t][m]);
        *(u16x8*)&out[(size_t)((i * SD + j) * SD + k0 + t) * 128 + c] = o;
    }
}

// ---------------------------------------------------------------------------
// shift-D + fc3 + GELU + residual + wave-local LN + coalesced f32x4 store.
// r19 version (unchanged): hoisted loads, 34 KB LDS, XCD swizzle (1728).
__global__ __launch_bounds__(256) void k_final(
    const u16* __restrict__ in, const u16* __restrict__ wfrag, const float* __restrict__ bias,
    const u16* __restrict__ tin, const float* __restrict__ gn, const float* __restrict__ bn,
    float* __restrict__ out)
{
    __shared__ __align__(16) unsigned char smem[34816];
    u16* wfl = (u16*)smem;
    float* Osm = (float*)smem;
    const int tid = threadIdx.x;
    const int n0 = xcd_swz1728(blockIdx.x) * 64;
    const int lane = tid & 63;
    const int wv = tid >> 6;
    const int colb = lane & 15;
    const int q = lane >> 4;

    for (int i = tid; i < 2048; i += 256)
        *(u16x8*)&wfl[i * 8] = *(const u16x8*)&wfrag[i * 8];

    const int nn = wv * 16 + colb;
    const int n = n0 + nn;
    const int coord = n % SD;

    u16x4 tq[8];
    #pragma unroll
    for (int ta = 0; ta < 8; ++ta)
        tq[ta] = *(const u16x4*)&tin[(size_t)n * 128 + ta * 16 + q * 4];
    s16x8 b4[4];
    #pragma unroll
    for (int s = 0; s < 4; ++s) {
        u16x8 bv = ld_shift8(in, n, coord, 1, s * 32 + q * 8);
        b4[s] = *(s16x8*)&bv;
    }

    f32x4 acc[8];
    #pragma unroll
    for (int ta = 0; ta < 8; ++ta)
        #pragma unroll
        for (int r4 = 0; r4 < 4; ++r4)
            acc[ta][r4] = bias[ta * 16 + q * 4 + r4];
    __syncthreads();

    #pragma unroll
    for (int s = 0; s < 4; ++s) {
        s16x8 af[8];
        #pragma unroll
        for (int ta = 0; ta < 8; ++ta)
            af[ta] = *(const s16x8*)&wfl[((ta * 4 + s) * 64 + lane) * 8];
        #pragma unroll
        for (int ta = 0; ta < 8; ++ta)
            acc[ta] = __builtin_amdgcn_mfma_f32_16x16x32_bf16(af[ta], b4[s], acc[ta], 0, 0, 0);
    }

    float s1 = 0.f, s2 = 0.f;
    #pragma unroll
    for (int ta = 0; ta < 8; ++ta)
        #pragma unroll
        for (int r4 = 0; r4 < 4; ++r4) {
            float v = gelu_f(acc[ta][r4]) + bf2f(tq[ta][r4]);
            acc[ta][r4] = v;
            s1 += v; s2 += v * v;
        }
    s1 += __shfl_xor(s1, 16); s2 += __shfl_xor(s2, 16);
    s1 += __shfl_xor(s1, 32); s2 += __shfl_xor(s2, 32);
    float mean = s1 * (1.f / 128.f);
    float var  = fmaxf(s2 * (1.f / 128.f) - mean * mean, 0.f);
    float rstd = rsqrtf(var + 1e-5f);

    __syncthreads();

    #pragma unroll
    for (int ta = 0; ta < 8; ++ta)
        #pragma unroll
        for (int r4 = 0; r4 < 4; ++r4) {
            int co = ta * 16 + q * 4 + r4;
            float o = (acc[ta][r4] - mean) * rstd * gn[co] + bn[co];
            Osm[co * 68 + nn] = o;
        }
    __syncthreads();

    #pragma unroll
    for (int it = 0; it < 8; ++it) {
        int idx = it * 256 + tid;
        int row = idx >> 4;
        int c4 = idx & 15;
        f32x4 v = *(const f32x4*)&Osm[row * 68 + c4 * 4];
        *(f32x4*)&out[(size_t)row * NTOT + n0 + c4 * 4] = v;
    }
}

// ---------------------------------------------------------------------------
extern "C" void kernel_launch(void* const* d_in, const int* in_sizes, int n_in,
                              void* d_out, int out_size, void* d_ws, size_t ws_size,
                              hipStream_t stream)
{
    const float* x    = (const float*)d_in[0];
    const float* pw   = (const float*)d_in[1];
    const float* pb   = (const float*)d_in[2];
    const float* g0   = (const float*)d_in[3];
    const float* b0   = (const float*)d_in[4];
    const float* g2   = (const float*)d_in[5];
    const float* b2   = (const float*)d_in[6];
    const float* fc1w = (const float*)d_in[7];
    const float* fc1b = (const float*)d_in[8];
    const float* dw1w = (const float*)d_in[9];
    const float* dw1b = (const float*)d_in[10];
    const float* fc2w = (const float*)d_in[11];
    const float* fc2b = (const float*)d_in[12];
    const float* dw2w = (const float*)d_in[13];
    const float* dw2b = (const float*)d_in[14];
    const float* fc3w = (const float*)d_in[15];
    const float* fc3b = (const float*)d_in[16];
    const float* gn   = (const float*)d_in[17];
    const float* bn   = (const float*)d_in[18];
    float* out = (float*)d_out;

    u16* tbuf = (u16*)d_ws;                      // NTOT*128 bf16
    u16* h1   = tbuf + (size_t)NTOT * 128;       // NTOT*128 bf16
    u16* h2   = h1 + (size_t)NTOT * 128;         // NTOT*128 bf16
    u16* wfP  = h2 + (size_t)NTOT * 128;         // 16384 u16 each
    u16* wf1  = wfP + 16384;
    u16* wf2  = wf1 + 16384;
    u16* wf3  = wf2 + 16384;
    float* dwT1 = (float*)(wf3 + 16384);         // 27*128 f32
    float* dwT2 = dwT1 + 27 * 128;
    float* mrs  = dwT2 + 27 * 128;               // NTOT*2 f32 row stats

    k_prep<<<60, 256, 0, stream>>>(pw, fc1w, fc2w, fc3w, dw1w, dw2w,
                                   wfP, wf1, wf2, wf3, dwT1, dwT2);

    k_proj_ln<<<NTOT / 128, 256, 0, stream>>>(x, wfP, pb, g0, b0, tbuf, mrs);
    k_shift_mm_ln<<<NTOT / 128, 256, 0, stream>>>(tbuf, mrs, g2, b2, wf1, fc1b, h2);
    k_dw<<<SWD, 256, 0, stream>>>(h2, dwT1, dw1b, h1);
    k_shift_mm<1><<<NTOT / 128, 256, 0, stream>>>(h1, wf2, fc2b, h2);
    k_dw<<<SWD, 256, 0, stream>>>(h2, dwT2, dw2b, h1);
    k_final<<<NTOT / 64, 256, 0, stream>>>(h1, wf3, fc3b, tbuf, gn, bn, out);
}

// Round 21
// 142.427 us; speedup vs baseline: 1.0692x; 1.0692x over previous
//
#include <hip/hip_runtime.h>
#include <hip/hip_bf16.h>
#include <math.h>

#define NTOT 110592   // 48^3
#define SD 48
#define SWD 2304      // 48*48

typedef short s16x8 __attribute__((ext_vector_type(8)));
typedef unsigned short u16x8 __attribute__((ext_vector_type(8)));
typedef unsigned short u16x4 __attribute__((ext_vector_type(4)));
typedef float f32x4 __attribute__((ext_vector_type(4)));
typedef unsigned short u16;

__device__ __forceinline__ float bf2f(u16 u) {
    unsigned int x = ((unsigned int)u) << 16;
    float f; __builtin_memcpy(&f, &x, 4); return f;
}
__device__ __forceinline__ u16 f2bf(float f) {
    __hip_bfloat16 h = __float2bfloat16(f);
    u16 u; __builtin_memcpy(&u, &h, 2); return u;
}
__device__ __forceinline__ u16x8 zero8() {
    u16x8 z;
    #pragma unroll
    for (int j = 0; j < 8; ++j) z[j] = 0;
    return z;
}

// fast GELU (tanh form): max abs dev from exact ~1e-3, far under tolerance
__device__ __forceinline__ float gelu_f(float x) {
    float y = x * (0.7978845608f + 0.0356774081f * x * x);
    float e = exp2f(y * 2.885390082f);
    return x - x * __builtin_amdgcn_rcpf(e + 1.f);
}

// XCD-chunked bijective block remap for 1728-block grids (1728 = 8*216)
__device__ __forceinline__ int xcd_swz(int bid) {
    return (bid & 7) * 216 + (bid >> 3);
}

// load shifted h[n][cbase..cbase+7] (bf16), axial shift along stride STR.
__device__ __forceinline__ u16x8 ld_shift8(const u16* __restrict__ in, int n, int coord,
                                           int STR, int cbase) {
    int g = cbase / 26;
    int split = 26 * (g + 1) - cbase;
    int sh0 = g - 2;
    int cs0 = coord - sh0;
    u16x8 lo = zero8();
    if (cs0 >= 0 && cs0 < SD) lo = *(const u16x8*)&in[(size_t)(n - sh0 * STR) * 128 + cbase];
    if (split >= 8) return lo;
    u16x8 hi = zero8();
    int cs1 = cs0 - 1;
    if (cs1 >= 0 && cs1 < SD) hi = *(const u16x8*)&in[(size_t)(n - (sh0 + 1) * STR) * 128 + cbase];
    u16x8 r;
    #pragma unroll
    for (int j = 0; j < 8; ++j) r[j] = (j < split) ? lo[j] : hi[j];
    return r;
}

// shifted gather from t with FUSED LN2 (axis H), zero-fill at boundaries.
__device__ __forceinline__ s16x8 ld_shift8_ln(const u16* __restrict__ t,
                                              const float* __restrict__ mrs,
                                              const float* __restrict__ g2,
                                              const float* __restrict__ b2,
                                              int n, int coord, int STR, int cbase) {
    int g = cbase / 26;
    int split = 26 * (g + 1) - cbase;
    int sh0 = g - 2;
    int cs0 = coord - sh0;
    float gg[8], bb[8];
    {
        f32x4 ga = *(const f32x4*)&g2[cbase];
        f32x4 gb = *(const f32x4*)&g2[cbase + 4];
        f32x4 ba = *(const f32x4*)&b2[cbase];
        f32x4 bbv = *(const f32x4*)&b2[cbase + 4];
        #pragma unroll
        for (int j = 0; j < 4; ++j) {
            gg[j] = ga[j]; gg[j + 4] = gb[j];
            bb[j] = ba[j]; bb[j + 4] = bbv[j];
        }
    }
    float lo[8];
    bool lov = (cs0 >= 0 && cs0 < SD);
    if (lov) {
        int r = n - sh0 * STR;
        u16x8 raw = *(const u16x8*)&t[(size_t)r * 128 + cbase];
        float m = mrs[2 * r], rs = mrs[2 * r + 1];
        #pragma unroll
        for (int j = 0; j < 8; ++j)
            lo[j] = (bf2f(raw[j]) - m) * rs * gg[j] + bb[j];
    } else {
        #pragma unroll
        for (int j = 0; j < 8; ++j) lo[j] = 0.f;
    }
    s16x8 out;
    if (split >= 8) {
        #pragma unroll
        for (int j = 0; j < 8; ++j) out[j] = (short)f2bf(lo[j]);
        return out;
    }
    float hi[8];
    int cs1 = cs0 - 1;
    bool hiv = (cs1 >= 0 && cs1 < SD);
    if (hiv) {
        int r = n - (sh0 + 1) * STR;
        u16x8 raw = *(const u16x8*)&t[(size_t)r * 128 + cbase];
        float m = mrs[2 * r], rs = mrs[2 * r + 1];
        #pragma unroll
        for (int j = 0; j < 8; ++j)
            hi[j] = (bf2f(raw[j]) - m) * rs * gg[j] + bb[j];
    } else {
        #pragma unroll
        for (int j = 0; j < 8; ++j) hi[j] = 0.f;
    }
    #pragma unroll
    for (int j = 0; j < 8; ++j)
        out[j] = (short)f2bf((j < split) ? lo[j] : hi[j]);
    return out;
}

// ---------------------------------------------------------------------------
// merged prep (unchanged)
__global__ __launch_bounds__(256) void k_prep(
    const float* __restrict__ pw, const float* __restrict__ fc1w,
    const float* __restrict__ fc2w, const float* __restrict__ fc3w,
    const float* __restrict__ dw1w, const float* __restrict__ dw2w,
    u16* __restrict__ wfP, u16* __restrict__ wf1, u16* __restrict__ wf2,
    u16* __restrict__ wf3, float* __restrict__ dwT1, float* __restrict__ dwT2)
{
    int b = blockIdx.x;
    if (b < 32) {
        int which = b >> 3;
        const float* src = (which == 0) ? pw : (which == 1) ? fc1w : (which == 2) ? fc2w : fc3w;
        u16* dst = (which == 0) ? wfP : (which == 1) ? wf1 : (which == 2) ? wf2 : wf3;
        int idx = (b & 7) * 256 + threadIdx.x;
        int lane = idx & 63;
        int s = (idx >> 6) & 3;
        int t = idx >> 8;
        int co = t * 16 + (lane & 15);
        int kb = s * 32 + (lane >> 4) * 8;
        #pragma unroll
        for (int j = 0; j < 8; ++j) {
            int kk = kb + j;
            float v;
            if (which == 0) {
                int tau = kk >> 2, ci = kk & 3;
                v = (tau < 27) ? src[co * 108 + ci * 27 + tau] : 0.f;
            } else {
                v = src[co * 128 + kk];
            }
            dst[idx * 8 + j] = f2bf(v);
        }
    } else {
        int which = (b - 32) / 14;
        int bb = (b - 32) % 14;
        const float* src = which ? dw2w : dw1w;
        float* dst = which ? dwT2 : dwT1;
        int idx = bb * 256 + threadIdx.x;
        if (idx < 27 * 128) {
            int k = idx >> 7;
            int co = idx & 127;
            dst[idx] = src[co * 27 + k];
        }
    }
}

// ---------------------------------------------------------------------------
// proj conv + LN0 -> t(bf16) + LN2 stats -> mrs. r17 structure + XCD swizzle.
__global__ __launch_bounds__(256) void k_proj_ln(
    const float* __restrict__ x, const u16* __restrict__ wfrag, const float* __restrict__ pb,
    const float* __restrict__ g0, const float* __restrict__ b0,
    u16* __restrict__ t_out, float* __restrict__ mrs)
{
    __shared__ __align__(16) u16 wfl[16384];   // 32 KB weight frags
    const int tid = threadIdx.x;
    const int n0 = xcd_swz(blockIdx.x) * 64;
    const int lane = tid & 63;
    const int wv = tid >> 6;
    const int colb = lane & 15;
    const int q = lane >> 4;

    for (int i = tid; i < 2048; i += 256)
        *(u16x8*)&wfl[i * 8] = *(const u16x8*)&wfrag[i * 8];

    const int arow = wv * 16 + colb;
    const int n = n0 + arow;
    const int oi = n / SWD;
    const int rem = n - oi * SWD;
    const int oj = rem / SD;
    const int ok = rem - oj * SD;
    const int ii0 = 2 * oi - 1, ij0 = 2 * oj - 1, ik0 = 2 * ok - 1;

    // HOISTED gather: all 32 predicated loads issued before the barrier
    s16x8 a4[4];
    #pragma unroll
    for (int s = 0; s < 4; ++s) {
        #pragma unroll
        for (int d = 0; d < 2; ++d) {
            int tq = 2 * q + d;
            int tau = s * 8 + tq;
            u16 v4[4] = {0, 0, 0, 0};
            bool valid = (s < 3) || (tq < 3);   // tau < 27
            if (valid) {
                int ti = (tau >= 18 ? 1 : 0) + (tau >= 9 ? 1 : 0);
                int r2 = tau - ti * 9;
                int tj = (r2 >= 6 ? 1 : 0) + (r2 >= 3 ? 1 : 0);
                int tk = r2 - tj * 3;
                int ii = ii0 + ti, ij = ij0 + tj, ik = ik0 + tk;
                if (ii >= 0 && ij >= 0 && ik >= 0) {
                    size_t off = ((size_t)ii * 96 + ij) * 96 + ik;
                    #pragma unroll
                    for (int ci = 0; ci < 4; ++ci)
                        v4[ci] = f2bf(x[(size_t)ci * 884736 + off]);
                }
            }
            a4[s][4 * d + 0] = (short)v4[0]; a4[s][4 * d + 1] = (short)v4[1];
            a4[s][4 * d + 2] = (short)v4[2]; a4[s][4 * d + 3] = (short)v4[3];
        }
    }

    f32x4 acc[8];
    #pragma unroll
    for (int t = 0; t < 8; ++t) {
        float bb = pb[t * 16 + colb];
        acc[t][0] = bb; acc[t][1] = bb; acc[t][2] = bb; acc[t][3] = bb;
    }
    __syncthreads();   // wfl ready

    #pragma unroll
    for (int s = 0; s < 4; ++s) {
        s16x8 bf[8];
        #pragma unroll
        for (int t = 0; t < 8; ++t)
            bf[t] = *(const s16x8*)&wfl[((t * 4 + s) * 64 + lane) * 8];
        #pragma unroll
        for (int t = 0; t < 8; ++t)
            acc[t] = __builtin_amdgcn_mfma_f32_16x16x32_bf16(a4[s], bf[t], acc[t], 0, 0, 0);
    }

    // LN0 stats
    float s1[4] = {0.f,0.f,0.f,0.f}, s2[4] = {0.f,0.f,0.f,0.f};
    #pragma unroll
    for (int t = 0; t < 8; ++t)
        #pragma unroll
        for (int r4 = 0; r4 < 4; ++r4) {
            float v = acc[t][r4];
            s1[r4] += v; s2[r4] += v * v;
        }
    #pragma unroll
    for (int r4 = 0; r4 < 4; ++r4)
        #pragma unroll
        for (int m = 1; m < 16; m <<= 1) {
            s1[r4] += __shfl_xor(s1[r4], m);
            s2[r4] += __shfl_xor(s2[r4], m);
        }

    float g0v[8], b0v[8];
    #pragma unroll
    for (int t = 0; t < 8; ++t) {
        int c = t * 16 + colb;
        g0v[t] = g0[c]; b0v[t] = b0[c];
    }

    float tval[8][4];
    float u1[4] = {0.f,0.f,0.f,0.f}, u2[4] = {0.f,0.f,0.f,0.f};
    #pragma unroll
    for (int r4 = 0; r4 < 4; ++r4) {
        float mean = s1[r4] * (1.f / 128.f);
        float var  = fmaxf(s2[r4] * (1.f / 128.f) - mean * mean, 0.f);
        float rstd = rsqrtf(var + 1e-5f);
        #pragma unroll
        for (int t = 0; t < 8; ++t) {
            float tv = (acc[t][r4] - mean) * rstd * g0v[t] + b0v[t];
            tval[t][r4] = tv;
            u1[r4] += tv; u2[r4] += tv * tv;
        }
    }
    #pragma unroll
    for (int r4 = 0; r4 < 4; ++r4) {
        #pragma unroll
        for (int m = 1; m < 16; m <<= 1) {
            u1[r4] += __shfl_xor(u1[r4], m);
            u2[r4] += __shfl_xor(u2[r4], m);
        }
    }

    #pragma unroll
    for (int r4 = 0; r4 < 4; ++r4) {
        float mean2 = u1[r4] * (1.f / 128.f);
        float var2  = fmaxf(u2[r4] * (1.f / 128.f) - mean2 * mean2, 0.f);
        float rstd2 = rsqrtf(var2 + 1e-5f);
        int row = wv * 16 + q * 4 + r4;
        size_t base = (size_t)(n0 + row) * 128;
        #pragma unroll
        for (int t = 0; t < 8; ++t)
            t_out[base + t * 16 + colb] = f2bf(tval[t][r4]);
        if (colb == 0) {
            mrs[2 * (n0 + row) + 0] = mean2;
            mrs[2 * (n0 + row) + 1] = rstd2;
        }
    }
}

// ---------------------------------------------------------------------------
// axial shift + FUSED LN2 + matmul (axis H) + XCD swizzle.
__global__ __launch_bounds__(256) void k_shift_mm_ln(
    const u16* __restrict__ tin, const float* __restrict__ mrs,
    const float* __restrict__ g2, const float* __restrict__ b2,
    const u16* __restrict__ wfrag, const float* __restrict__ bias,
    u16* __restrict__ out)
{
    __shared__ __align__(16) u16 wfl[16384];
    const int tid = threadIdx.x;
    const int n0 = xcd_swz(blockIdx.x) * 64;
    const int lane = tid & 63;
    const int wv = tid >> 6;
    const int colb = lane & 15;
    const int q = lane >> 4;

    for (int i = tid; i < 2048; i += 256)
        *(u16x8*)&wfl[i * 8] = *(const u16x8*)&wfrag[i * 8];

    const int arow = wv * 16 + colb;
    const int n = n0 + arow;
    const int coord = n / SWD;         // axis H, STR = SWD

    s16x8 a4[4];
    #pragma unroll
    for (int s = 0; s < 4; ++s)
        a4[s] = ld_shift8_ln(tin, mrs, g2, b2, n, coord, SWD, s * 32 + q * 8);

    f32x4 acc[8];
    #pragma unroll
    for (int t = 0; t < 8; ++t) {
        float bb = bias[t * 16 + colb];
        acc[t][0] = bb; acc[t][1] = bb; acc[t][2] = bb; acc[t][3] = bb;
    }
    __syncthreads();
    #pragma unroll
    for (int s = 0; s < 4; ++s) {
        s16x8 bf[8];
        #pragma unroll
        for (int t = 0; t < 8; ++t)
            bf[t] = *(const s16x8*)&wfl[((t * 4 + s) * 64 + lane) * 8];
        #pragma unroll
        for (int t = 0; t < 8; ++t)
            acc[t] = __builtin_amdgcn_mfma_f32_16x16x32_bf16(a4[s], bf[t], acc[t], 0, 0, 0);
    }
    #pragma unroll
    for (int r4 = 0; r4 < 4; ++r4) {
        int row = wv * 16 + q * 4 + r4;
        size_t base = (size_t)(n0 + row) * 128;
        #pragma unroll
        for (int t = 0; t < 8; ++t)
            out[base + t * 16 + colb] = f2bf(acc[t][r4]);
    }
}

// ---------------------------------------------------------------------------
// axial shift + matmul (plain, axis W) + XCD swizzle.
template <int AXIS>
__global__ __launch_bounds__(256) void k_shift_mm(
    const u16* __restrict__ in, const u16* __restrict__ wfrag, const float* __restrict__ bias,
    u16* __restrict__ out)
{
    __shared__ __align__(16) u16 wfl[16384];
    const int tid = threadIdx.x;
    const int n0 = xcd_swz(blockIdx.x) * 64;
    const int lane = tid & 63;
    const int wv = tid >> 6;
    const int colb = lane & 15;
    const int q = lane >> 4;

    for (int i = tid; i < 2048; i += 256)
        *(u16x8*)&wfl[i * 8] = *(const u16x8*)&wfrag[i * 8];

    const int arow = wv * 16 + colb;
    const int n = n0 + arow;
    const int STR = (AXIS == 0) ? SWD : (AXIS == 1) ? SD : 1;
    const int coord = (AXIS == 0) ? n / SWD : (AXIS == 1) ? (n / SD) % SD : n % SD;

    s16x8 a4[4];
    #pragma unroll
    for (int s = 0; s < 4; ++s) {
        u16x8 av = ld_shift8(in, n, coord, STR, s * 32 + q * 8);
        a4[s] = *(s16x8*)&av;
    }

    f32x4 acc[8];
    #pragma unroll
    for (int t = 0; t < 8; ++t) {
        float bb = bias[t * 16 + colb];
        acc[t][0] = bb; acc[t][1] = bb; acc[t][2] = bb; acc[t][3] = bb;
    }
    __syncthreads();
    #pragma unroll
    for (int s = 0; s < 4; ++s) {
        s16x8 bf[8];
        #pragma unroll
        for (int t = 0; t < 8; ++t)
            bf[t] = *(const s16x8*)&wfl[((t * 4 + s) * 64 + lane) * 8];
        #pragma unroll
        for (int t = 0; t < 8; ++t)
            acc[t] = __builtin_amdgcn_mfma_f32_16x16x32_bf16(a4[s], bf[t], acc[t], 0, 0, 0);
    }
    #pragma unroll
    for (int r4 = 0; r4 < 4; ++r4) {
        int row = wv * 16 + q * 4 + r4;
        size_t base = (size_t)(n0 + row) * 128;
        #pragma unroll
        for (int t = 0; t < 8; ++t)
            out[base + t * 16 + colb] = f2bf(acc[t][r4]);
    }
}

// ---------------------------------------------------------------------------
// depthwise 3x3x3 conv (unchanged)
__global__ __launch_bounds__(256, 4) void k_dw(
    const u16* __restrict__ in, const float* __restrict__ wt, const float* __restrict__ b,
    u16* __restrict__ out)
{
    __shared__ __align__(16) float wtl[27 * 128];
    const int tid = threadIdx.x;
    const int cg = tid & 15;
    const int kq = tid >> 4;
    const int k0 = kq * 3;
    const int bid = blockIdx.x;
    const int ij = (bid & 7) * 288 + (bid >> 3);
    const int i = ij / SD;
    const int j = ij - i * SD;
    const int c = cg * 8;

    for (int t = tid; t < 864; t += 256)
        ((float4*)wtl)[t] = ((const float4*)wt)[t];

    const int kclamp0 = (k0 - 1 < 0) ? 0 : (k0 - 1);
    const int kclamp4 = (k0 + 3 > SD - 1) ? (SD - 1) : (k0 + 3);
    const bool k0bad = (k0 - 1 < 0);
    const bool k4bad = (k0 + 3 > SD - 1);

    float acc[3][8];
    {
        float4 ba = *(const float4*)&b[c];
        float4 bb = *(const float4*)&b[c + 4];
        #pragma unroll
        for (int t = 0; t < 3; ++t) {
            acc[t][0] = ba.x; acc[t][1] = ba.y; acc[t][2] = ba.z; acc[t][3] = ba.w;
            acc[t][4] = bb.x; acc[t][5] = bb.y; acc[t][6] = bb.z; acc[t][7] = bb.w;
        }
    }

    bool okt[9];
    const u16* baseptr[9];
    #pragma unroll
    for (int t9 = 0; t9 < 9; ++t9) {
        int di = t9 / 3 - 1, dj = t9 % 3 - 1;
        int ii = i + di, jj = j + dj;
        okt[t9] = ((unsigned)ii < SD) && ((unsigned)jj < SD);
        int iic = (ii < 0) ? 0 : (ii > SD - 1 ? SD - 1 : ii);
        int jjc = (jj < 0) ? 0 : (jj > SD - 1 ? SD - 1 : jj);
        baseptr[t9] = &in[(size_t)((iic * SD + jjc) * SD) * 128 + c];
    }

    u16x8 win[2][5];
    {
        const u16* base = baseptr[0];
        win[0][0] = *(const u16x8*)(base + (size_t)kclamp0 * 128);
        win[0][1] = *(const u16x8*)(base + (size_t)(k0    ) * 128);
        win[0][2] = *(const u16x8*)(base + (size_t)(k0 + 1) * 128);
        win[0][3] = *(const u16x8*)(base + (size_t)(k0 + 2) * 128);
        win[0][4] = *(const u16x8*)(base + (size_t)kclamp4 * 128);
    }
    __syncthreads();

    #pragma unroll
    for (int t9 = 0; t9 < 9; ++t9) {
        const int cur = t9 & 1;
        if (t9 < 8) {
            const u16* base = baseptr[t9 + 1];
            win[cur ^ 1][0] = *(const u16x8*)(base + (size_t)kclamp0 * 128);
            win[cur ^ 1][1] = *(const u16x8*)(base + (size_t)(k0    ) * 128);
            win[cur ^ 1][2] = *(const u16x8*)(base + (size_t)(k0 + 1) * 128);
            win[cur ^ 1][3] = *(const u16x8*)(base + (size_t)(k0 + 2) * 128);
            win[cur ^ 1][4] = *(const u16x8*)(base + (size_t)kclamp4 * 128);
        }
        if (okt[t9]) {
            const int tap0 = t9 * 3;
            float wv[3][8];
            #pragma unroll
            for (int dk = 0; dk < 3; ++dk) {
                float4 wa = *(const float4*)&wtl[(tap0 + dk) * 128 + c];
                float4 wb = *(const float4*)&wtl[(tap0 + dk) * 128 + c + 4];
                wv[dk][0] = wa.x; wv[dk][1] = wa.y; wv[dk][2] = wa.z; wv[dk][3] = wa.w;
                wv[dk][4] = wb.x; wv[dk][5] = wb.y; wv[dk][6] = wb.z; wv[dk][7] = wb.w;
            }
            #pragma unroll
            for (int s = 0; s < 5; ++s) {
                bool bad = (s == 0 && k0bad) || (s == 4 && k4bad);
                float vs[8];
                #pragma unroll
                for (int m = 0; m < 8; ++m)
                    vs[m] = bad ? 0.f : bf2f(win[cur][s][m]);
                #pragma unroll
                for (int t = 0; t < 3; ++t) {
                    int dk = s - t;
                    if (dk >= 0 && dk < 3) {
                        #pragma unroll
                        for (int m = 0; m < 8; ++m)
                            acc[t][m] = fmaf(wv[dk][m], vs[m], acc[t][m]);
                    }
                }
            }
        }
    }
    #pragma unroll
    for (int t = 0; t < 3; ++t) {
        u16x8 o;
        #pragma unroll
        for (int m = 0; m < 8; ++m) o[m] = f2bf(acc[t][m]);
        *(u16x8*)&out[(size_t)((i * SD + j) * SD + k0 + t) * 128 + c] = o;
    }
}

// ---------------------------------------------------------------------------
// shift-D + fc3 + GELU + residual + wave-local LN + coalesced f32x4 store.
// r16/r17 structure (hoisted loads, 34 KB LDS) + XCD swizzle.
__global__ __launch_bounds__(256) void k_final(
    const u16* __restrict__ in, const u16* __restrict__ wfrag, const float* __restrict__ bias,
    const u16* __restrict__ tin, const float* __restrict__ gn, const float* __restrict__ bn,
    float* __restrict__ out)
{
    __shared__ __align__(16) unsigned char smem[34816];
    u16* wfl = (u16*)smem;                    // 32 KB weight frags
    float* Osm = (float*)smem;                // 128*68 f32 (overlay)
    const int tid = threadIdx.x;
    const int n0 = xcd_swz(blockIdx.x) * 64;
    const int lane = tid & 63;
    const int wv = tid >> 6;
    const int colb = lane & 15;
    const int q = lane >> 4;

    for (int i = tid; i < 2048; i += 256)
        *(u16x8*)&wfl[i * 8] = *(const u16x8*)&wfrag[i * 8];

    const int nn = wv * 16 + colb;
    const int n = n0 + nn;
    const int coord = n % SD;

    u16x4 tq[8];
    #pragma unroll
    for (int ta = 0; ta < 8; ++ta)
        tq[ta] = *(const u16x4*)&tin[(size_t)n * 128 + ta * 16 + q * 4];
    s16x8 b4[4];
    #pragma unroll
    for (int s = 0; s < 4; ++s) {
        u16x8 bv = ld_shift8(in, n, coord, 1, s * 32 + q * 8);
        b4[s] = *(s16x8*)&bv;
    }

    f32x4 acc[8];
    #pragma unroll
    for (int ta = 0; ta < 8; ++ta)
        #pragma unroll
        for (int r4 = 0; r4 < 4; ++r4)
            acc[ta][r4] = bias[ta * 16 + q * 4 + r4];
    __syncthreads();   // wfl ready

    #pragma unroll
    for (int s = 0; s < 4; ++s) {
        s16x8 af[8];
        #pragma unroll
        for (int ta = 0; ta < 8; ++ta)
            af[ta] = *(const s16x8*)&wfl[((ta * 4 + s) * 64 + lane) * 8];
        #pragma unroll
        for (int ta = 0; ta < 8; ++ta)
            acc[ta] = __builtin_amdgcn_mfma_f32_16x16x32_bf16(af[ta], b4[s], acc[ta], 0, 0, 0);
    }

    float s1 = 0.f, s2 = 0.f;
    #pragma unroll
    for (int ta = 0; ta < 8; ++ta)
        #pragma unroll
        for (int r4 = 0; r4 < 4; ++r4) {
            float v = gelu_f(acc[ta][r4]) + bf2f(tq[ta][r4]);
            acc[ta][r4] = v;
            s1 += v; s2 += v * v;
        }
    s1 += __shfl_xor(s1, 16); s2 += __shfl_xor(s2, 16);
    s1 += __shfl_xor(s1, 32); s2 += __shfl_xor(s2, 32);
    float mean = s1 * (1.f / 128.f);
    float var  = fmaxf(s2 * (1.f / 128.f) - mean * mean, 0.f);
    float rstd = rsqrtf(var + 1e-5f);

    __syncthreads();   // wfl dead; Osm overlay safe

    #pragma unroll
    for (int ta = 0; ta < 8; ++ta)
        #pragma unroll
        for (int r4 = 0; r4 < 4; ++r4) {
            int co = ta * 16 + q * 4 + r4;
            float o = (acc[ta][r4] - mean) * rstd * gn[co] + bn[co];
            Osm[co * 68 + nn] = o;
        }
    __syncthreads();

    #pragma unroll
    for (int it = 0; it < 8; ++it) {
        int idx = it * 256 + tid;
        int row = idx >> 4;
        int c4 = idx & 15;
        f32x4 v = *(const f32x4*)&Osm[row * 68 + c4 * 4];
        *(f32x4*)&out[(size_t)row * NTOT + n0 + c4 * 4] = v;
    }
}

// ---------------------------------------------------------------------------
extern "C" void kernel_launch(void* const* d_in, const int* in_sizes, int n_in,
                              void* d_out, int out_size, void* d_ws, size_t ws_size,
                              hipStream_t stream)
{
    const float* x    = (const float*)d_in[0];
    const float* pw   = (const float*)d_in[1];
    const float* pb   = (const float*)d_in[2];
    const float* g0   = (const float*)d_in[3];
    const float* b0   = (const float*)d_in[4];
    const float* g2   = (const float*)d_in[5];
    const float* b2   = (const float*)d_in[6];
    const float* fc1w = (const float*)d_in[7];
    const float* fc1b = (const float*)d_in[8];
    const float* dw1w = (const float*)d_in[9];
    const float* dw1b = (const float*)d_in[10];
    const float* fc2w = (const float*)d_in[11];
    const float* fc2b = (const float*)d_in[12];
    const float* dw2w = (const float*)d_in[13];
    const float* dw2b = (const float*)d_in[14];
    const float* fc3w = (const float*)d_in[15];
    const float* fc3b = (const float*)d_in[16];
    const float* gn   = (const float*)d_in[17];
    const float* bn   = (const float*)d_in[18];
    float* out = (float*)d_out;

    u16* tbuf = (u16*)d_ws;                      // NTOT*128 bf16
    u16* h1   = tbuf + (size_t)NTOT * 128;       // NTOT*128 bf16
    u16* h2   = h1 + (size_t)NTOT * 128;         // NTOT*128 bf16
    u16* wfP  = h2 + (size_t)NTOT * 128;         // 16384 u16 each
    u16* wf1  = wfP + 16384;
    u16* wf2  = wf1 + 16384;
    u16* wf3  = wf2 + 16384;
    float* dwT1 = (float*)(wf3 + 16384);         // 27*128 f32
    float* dwT2 = dwT1 + 27 * 128;
    float* mrs  = dwT2 + 27 * 128;               // NTOT*2 f32 row stats

    k_prep<<<60, 256, 0, stream>>>(pw, fc1w, fc2w, fc3w, dw1w, dw2w,
                                   wfP, wf1, wf2, wf3, dwT1, dwT2);

    k_proj_ln<<<NTOT / 64, 256, 0, stream>>>(x, wfP, pb, g0, b0, tbuf, mrs);
    k_shift_mm_ln<<<NTOT / 64, 256, 0, stream>>>(tbuf, mrs, g2, b2, wf1, fc1b, h2);
    k_dw<<<SWD, 256, 0, stream>>>(h2, dwT1, dw1b, h1);
    k_shift_mm<1><<<NTOT / 64, 256, 0, stream>>>(h1, wf2, fc2b, h2);
    k_dw<<<SWD, 256, 0, stream>>>(h2, dwT2, dw2b, h1);
    k_final<<<NTOT / 64, 256, 0, stream>>>(h1, wf3, fc3b, tbuf, gn, bn, out);
}